// Round 2
// baseline (4392.442 us; speedup 1.0000x reference)
//
#include <hip/hip_runtime.h>

#define B_TOT 4096
#define T_LEN 256
#define NCH   32

__device__ __forceinline__ float sigf(float x) { return 1.0f / (1.0f + expf(-x)); }

// sin/cos via Cody-Waite pi-reduction + Taylor (deg 11/12). abs err ~1e-7 on |x|<~100.
__device__ __forceinline__ void fast_sincos(float x, float& s, float& c) {
    float k = rintf(x * 0.3183098861837907f);
    float r = fmaf(-k, 3.14159274101257324f, x);      // pi_hi = float(pi)
    r = fmaf(-k, -8.74227765734758577e-8f, r);        // pi_lo = pi - pi_hi
    float r2 = r * r;
    float sp = -2.50521084e-8f;
    sp = fmaf(sp, r2, 2.75573192e-6f);
    sp = fmaf(sp, r2, -1.98412698e-4f);
    sp = fmaf(sp, r2, 8.33333333e-3f);
    sp = fmaf(sp, r2, -1.66666667e-1f);
    float sv = fmaf(sp * r2, r, r);
    float cp = 2.08767570e-9f;
    cp = fmaf(cp, r2, -2.75573192e-7f);
    cp = fmaf(cp, r2, 2.48015873e-5f);
    cp = fmaf(cp, r2, -1.38888889e-3f);
    cp = fmaf(cp, r2, 4.16666667e-2f);
    cp = fmaf(cp, r2, -0.5f);
    float cv = fmaf(cp, r2, 1.0f);
    float sgn = ((int)k & 1) ? -1.0f : 1.0f;          // sin(r+k*pi) = (-1)^k sin(r)
    s = sv * sgn;
    c = cv * sgn;
}

// ---------------- TCN: 3x (conv1d k=3 'same' + bias + ReLU) ----------------
__global__ __launch_bounds__(256) void tcn_kernel(
    const float* __restrict__ x,
    const float* __restrict__ cw1, const float* __restrict__ cb1,
    const float* __restrict__ cw2, const float* __restrict__ cb2,
    const float* __restrict__ cw3, const float* __restrict__ cb3,
    float* __restrict__ out)
{
    __shared__ float bufA[NCH * 257];
    __shared__ float bufB[NCH * 257];
    __shared__ float sW[NCH * 97];
    __shared__ float sB[NCH];

    const int b   = blockIdx.x;
    const int tid = threadIdx.x;
    const float* xb = x + (size_t)b * T_LEN * NCH;

    #pragma unroll
    for (int c = 0; c < 32; ++c) {
        int idx = c * 256 + tid;
        int t = idx >> 5, f = idx & 31;
        bufA[f * 257 + t] = xb[idx];
    }
    __syncthreads();

    float* bin  = bufA;
    float* bout = bufB;
    const int o  = tid & 31;
    const int t0 = (tid >> 5) * 32;

    for (int layer = 0; layer < 3; ++layer) {
        const float* Wg = (layer == 0) ? cw1 : ((layer == 1) ? cw2 : cw3);
        const float* Bg = (layer == 0) ? cb1 : ((layer == 1) ? cb2 : cb3);
        for (int idx = tid; idx < 32 * 96; idx += 256) {
            int oo = idx / 96, rem = idx - oo * 96;
            sW[oo * 97 + rem] = Wg[idx];
        }
        if (tid < 32) sB[tid] = Bg[tid];
        __syncthreads();

        float acc[32];
        const float bias = sB[o];
        #pragma unroll
        for (int tt = 0; tt < 32; ++tt) acc[tt] = bias;

        for (int i = 0; i < 32; ++i) {
            const float w0 = sW[o * 97 + i * 3 + 0];
            const float w1 = sW[o * 97 + i * 3 + 1];
            const float w2 = sW[o * 97 + i * 3 + 2];
            const float* row = bin + i * 257;
            float vm = (t0 == 0) ? 0.0f : row[t0 - 1];
            float v0 = row[t0];
            #pragma unroll
            for (int tt = 0; tt < 32; ++tt) {
                float vp = (t0 + tt == 255) ? 0.0f : row[t0 + tt + 1];
                acc[tt] = fmaf(w0, vm, acc[tt]);
                acc[tt] = fmaf(w1, v0, acc[tt]);
                acc[tt] = fmaf(w2, vp, acc[tt]);
                vm = v0; v0 = vp;
            }
        }
        #pragma unroll
        for (int tt = 0; tt < 32; ++tt)
            bout[o * 257 + t0 + tt] = fmaxf(acc[tt], 0.0f);
        __syncthreads();
        float* tmp = bin; bin = bout; bout = tmp;
    }

    float* og = out + (size_t)b * T_LEN * NCH;
    #pragma unroll
    for (int c = 0; c < 32; ++c) {
        int idx = c * 256 + tid;
        int t = idx >> 5, f = idx & 31;
        og[idx] = bin[f * 257 + t];
    }
}

// ---------------- recurrent scan: 1 batch row per wave ----------------
__global__ __launch_bounds__(256, 4) void scan_kernel(
    const float* __restrict__ tcn,
    const float* __restrict__ W_ih, const float* __restrict__ W_hh,
    const float* __restrict__ b_ih, const float* __restrict__ b_hh,
    const float* __restrict__ qw,
    const float* __restrict__ Wq, const float* __restrict__ bq,
    const float* __restrict__ Wo, const float* __restrict__ bo,
    float* __restrict__ out)
{
    // combined weight rows: sW[g][0..31]=W_ih[g], [32..63]=W_hh[g]; pad 68 (16B-aligned, even banks)
    __shared__ __align__(16) float sW[128 * 68];
    __shared__ __align__(16) float sxc[4][64];   // per wave: [0..31]=x_t, [32..63]=h

    const int tid = threadIdx.x;
    for (int idx = tid; idx < 128 * 64; idx += 256) {
        int g = idx >> 6, k = idx & 63;
        sW[g * 68 + k] = (k < 32) ? W_ih[g * 32 + k] : W_hh[g * 32 + (k - 32)];
    }
    __syncthreads();

    const int w    = tid >> 6;
    const int lane = tid & 63;
    const int b    = blockIdx.x * 4 + w;
    const float* xrow = tcn + (size_t)b * T_LEN * NCH;
    float* xc = sxc[w];

    const float bias0 = b_ih[lane] + b_hh[lane];
    const float bias1 = b_ih[lane + 64] + b_hh[lane + 64];

    // variational RY half-angle trig (constant over steps)
    float cwv[18], swv[18];
    #pragma unroll
    for (int i = 0; i < 18; ++i) fast_sincos(0.5f * qw[i], swv[i], cwv[i]);

    // CNOT-ring permutation source index (composition of 6 CNOTs, GF(2)-linear)
    int psrc = lane;
    psrc ^= (psrc & 1) << 5;    // CNOT(5,0)
    psrc ^= (psrc & 2) >> 1;    // CNOT(4,5)
    psrc ^= (psrc & 4) >> 1;    // CNOT(3,4)
    psrc ^= (psrc & 8) >> 1;    // CNOT(2,3)
    psrc ^= (psrc & 16) >> 1;   // CNOT(1,2)
    psrc ^= (psrc & 32) >> 1;   // CNOT(0,1)

    float wqr[6], bqr = 0.0f, wor = 0.0f;
    #pragma unroll
    for (int k = 0; k < 6; ++k) wqr[k] = 0.0f;
    if (lane < 32) {
        #pragma unroll
        for (int k = 0; k < 6; ++k) wqr[k] = Wq[lane * 6 + k];
        bqr = bq[lane];
        wor = Wo[lane];
    }

    const float4* xq  = (const float4*)xc;
    const float4* w0q = (const float4*)(sW + lane * 68);
    const float4* w1q = (const float4*)(sW + (lane + 64) * 68);

    float hh = 0.0f, cx = 0.0f;
    float xpre = (lane < 32) ? xrow[lane] : 0.0f;

    for (int t = 0; t < T_LEN; ++t) {
        if (lane < 32) {
            xc[lane]      = xpre;   // x_t
            xc[32 + lane] = hh;     // h_{t-1}
        }
        float xnext = (lane < 32 && t < T_LEN - 1) ? xrow[(t + 1) * 32 + lane] : 0.0f;

        // gates: acc0 = gates[lane] (i|f), acc1 = gates[lane+64] (g|o)
        float a0 = bias0, a1 = bias1, b0 = 0.0f, b1 = 0.0f;
        #pragma unroll
        for (int kc = 0; kc < 16; kc += 2) {
            float4 xv = xq[kc];
            float4 u0 = w0q[kc];
            float4 u1 = w1q[kc];
            a0 = fmaf(u0.x, xv.x, a0); a0 = fmaf(u0.y, xv.y, a0);
            a0 = fmaf(u0.z, xv.z, a0); a0 = fmaf(u0.w, xv.w, a0);
            a1 = fmaf(u1.x, xv.x, a1); a1 = fmaf(u1.y, xv.y, a1);
            a1 = fmaf(u1.z, xv.z, a1); a1 = fmaf(u1.w, xv.w, a1);
            float4 xv2 = xq[kc + 1];
            float4 v0  = w0q[kc + 1];
            float4 v1  = w1q[kc + 1];
            b0 = fmaf(v0.x, xv2.x, b0); b0 = fmaf(v0.y, xv2.y, b0);
            b0 = fmaf(v0.z, xv2.z, b0); b0 = fmaf(v0.w, xv2.w, b0);
            b1 = fmaf(v1.x, xv2.x, b1); b1 = fmaf(v1.y, xv2.y, b1);
            b1 = fmaf(v1.z, xv2.z, b1); b1 = fmaf(v1.w, xv2.w, b1);
        }
        float acc0 = a0 + b0, acc1 = a1 + b1;

        float fg = __shfl_xor(acc0, 32, 64);
        float og = __shfl_xor(acc1, 32, 64);
        float c  = sigf(fg) * cx + sigf(acc0) * tanhf(acc1);
        float h  = sigf(og) * tanhf(c);
        h = 3.99f * h * (1.0f - h);                       // logistic map
        float h0 = __shfl(h, 0, 64);
        float h1 = __shfl(h, 1, 64);
        if (lane == 0)      h = 1.0f - 1.4f * h0 * h0 + h1; // henon
        else if (lane == 1) h = 0.3f * h0;
        cx = c;

        // half-angle sincos of h[0..5]
        float ca[6], sa[6];
        #pragma unroll
        for (int i = 0; i < 6; ++i) {
            float ang = 0.5f * __shfl(h, i, 64);
            fast_sincos(ang, sa[i], ca[i]);
        }

        float re = (lane == 0) ? 1.0f : 0.0f;
        float im = 0.0f;

        // encoding: fused U = RZ(a[i+2]) * RY(a[i+1]) * RX(a[i]) per wire
        #pragma unroll
        for (int i = 0; i < 6; ++i) {
            const int jy = (i + 1) % 6, jz = (i + 2) % 6;
            float cx_ = ca[i],  sx_ = sa[i];
            float cy_ = ca[jy], sy_ = sa[jy];
            float cz_ = ca[jz], sz_ = sa[jz];
            float A  = cy_ * cx_, Bv = sy_ * sx_;
            float Cv = sy_ * cx_, Dv = cy_ * sx_;
            float ur  = fmaf(Bv, sz_, A * cz_);    // Re m00
            float ui  = fmaf(Bv, cz_, -(A * sz_)); // Im m00
            float pv  = fmaf(Dv, sz_, Cv * cz_);   // Re m10
            float qv_ = fmaf(Cv, sz_, -(Dv * cz_));// Im m10 (= Im m01)
            const int m = 32 >> i;
            const bool hi = (lane & m) != 0;
            float pre = __shfl_xor(re, m, 64), pim = __shfl_xor(im, m, 64);
            float si = hi ? -ui : ui;              // diag imag
            float po = hi ? pv : -pv;              // off real
            float nr = ur * re; nr = fmaf(-si, im, nr); nr = fmaf(po, pre, nr); nr = fmaf(-qv_, pim, nr);
            float ni = ur * im; ni = fmaf( si, re, ni); ni = fmaf(po, pim, ni); ni = fmaf( qv_, pre, ni);
            re = nr; im = ni;
        }

        // 3 variational layers: 6x RY + single bpermute for the CNOT ring
        #pragma unroll
        for (int l = 0; l < 3; ++l) {
            #pragma unroll
            for (int q = 0; q < 6; ++q) {
                const int m = 32 >> q;
                float pre = __shfl_xor(re, m, 64), pim = __shfl_xor(im, m, 64);
                float cc = cwv[l * 6 + q];
                float ss = (lane & m) ? swv[l * 6 + q] : -swv[l * 6 + q];
                re = fmaf(ss, pre, cc * re);
                im = fmaf(ss, pim, cc * im);
            }
            re = __shfl(re, psrc, 64);
            im = __shfl(im, psrc, 64);
        }

        // probs -> all 6 <Z_i> via Walsh-Hadamard butterfly
        float p = re * re + im * im;
        #pragma unroll
        for (int st = 0; st < 6; ++st) {
            const int m = 1 << st;
            float pp = __shfl_xor(p, m, 64);
            p = (lane & m) ? (pp - p) : (p + pp);
        }
        float upd = bqr;
        #pragma unroll
        for (int k = 0; k < 6; ++k) {
            float ev = __shfl(p, 32 >> k, 64);
            upd = fmaf(ev, wqr[k], upd);
        }
        hh = h + upd;
        xpre = xnext;
    }

    float contrib = (lane < 32) ? hh * wor : 0.0f;
    #pragma unroll
    for (int off = 32; off >= 1; off >>= 1)
        contrib += __shfl_xor(contrib, off, 64);
    if (lane == 0) out[b] = sigf(contrib + bo[0]);
}

extern "C" void kernel_launch(void* const* d_in, const int* in_sizes, int n_in,
                              void* d_out, int out_size, void* d_ws, size_t ws_size,
                              hipStream_t stream)
{
    const float* x    = (const float*)d_in[0];
    const float* cw1  = (const float*)d_in[1];
    const float* cb1  = (const float*)d_in[2];
    const float* cw2  = (const float*)d_in[3];
    const float* cb2  = (const float*)d_in[4];
    const float* cw3  = (const float*)d_in[5];
    const float* cb3  = (const float*)d_in[6];
    const float* W_ih = (const float*)d_in[7];
    const float* W_hh = (const float*)d_in[8];
    const float* b_ih = (const float*)d_in[9];
    const float* b_hh = (const float*)d_in[10];
    const float* qw   = (const float*)d_in[11];
    const float* Wq   = (const float*)d_in[12];
    const float* bq   = (const float*)d_in[13];
    const float* Wo   = (const float*)d_in[14];
    const float* bo   = (const float*)d_in[15];

    float* tcn = (float*)d_ws;  // [4096][256][32] f32 = 128 MiB scratch

    hipLaunchKernelGGL(tcn_kernel, dim3(B_TOT), dim3(256), 0, stream,
                       x, cw1, cb1, cw2, cb2, cw3, cb3, tcn);
    hipLaunchKernelGGL(scan_kernel, dim3(B_TOT / 4), dim3(256), 0, stream,
                       tcn, W_ih, W_hh, b_ih, b_hh, qw, Wq, bq, Wo, bo,
                       (float*)d_out);
}

// Round 3
// 1559.001 us; speedup vs baseline: 2.8175x; 2.8175x over previous
//
#include <hip/hip_runtime.h>

#define B_TOT 4096
#define T_LEN 256
#define NCH   32

__device__ __forceinline__ float sigf(float x) { return 1.0f / (1.0f + expf(-x)); }

__device__ __forceinline__ float rdlane(float v, int l) {
    return __int_as_float(__builtin_amdgcn_readlane(__float_as_int(v), l));
}
// xor-1 / xor-2 lane swaps on the VALU pipe (DPP quad_perm) instead of LDS
__device__ __forceinline__ float xor1f(float x) {
    return __int_as_float(__builtin_amdgcn_mov_dpp(__float_as_int(x), 0xB1, 0xF, 0xF, true));
}
__device__ __forceinline__ float xor2f(float x) {
    return __int_as_float(__builtin_amdgcn_mov_dpp(__float_as_int(x), 0x4E, 0xF, 0xF, true));
}

// sin/cos via Cody-Waite pi-reduction + Taylor (deg 11/12). abs err ~1e-7.
__device__ __forceinline__ void fast_sincos(float x, float& s, float& c) {
    float k = rintf(x * 0.3183098861837907f);
    float r = fmaf(-k, 3.14159274101257324f, x);
    r = fmaf(-k, -8.74227765734758577e-8f, r);
    float r2 = r * r;
    float sp = -2.50521084e-8f;
    sp = fmaf(sp, r2, 2.75573192e-6f);
    sp = fmaf(sp, r2, -1.98412698e-4f);
    sp = fmaf(sp, r2, 8.33333333e-3f);
    sp = fmaf(sp, r2, -1.66666667e-1f);
    float sv = fmaf(sp * r2, r, r);
    float cp = 2.08767570e-9f;
    cp = fmaf(cp, r2, -2.75573192e-7f);
    cp = fmaf(cp, r2, 2.48015873e-5f);
    cp = fmaf(cp, r2, -1.38888889e-3f);
    cp = fmaf(cp, r2, 4.16666667e-2f);
    cp = fmaf(cp, r2, -0.5f);
    float cv = fmaf(cp, r2, 1.0f);
    float sgn = ((int)k & 1) ? -1.0f : 1.0f;
    s = sv * sgn;
    c = cv * sgn;
}

// ---------------- TCN: 3x (conv1d k=3 'same' + bias + ReLU) ----------------
__global__ __launch_bounds__(256) void tcn_kernel(
    const float* __restrict__ x,
    const float* __restrict__ cw1, const float* __restrict__ cb1,
    const float* __restrict__ cw2, const float* __restrict__ cb2,
    const float* __restrict__ cw3, const float* __restrict__ cb3,
    float* __restrict__ out)
{
    __shared__ float bufA[NCH * 257];
    __shared__ float bufB[NCH * 257];
    __shared__ float sW[NCH * 97];
    __shared__ float sB[NCH];

    const int b   = blockIdx.x;
    const int tid = threadIdx.x;
    const float* xb = x + (size_t)b * T_LEN * NCH;

    #pragma unroll
    for (int c = 0; c < 32; ++c) {
        int idx = c * 256 + tid;
        int t = idx >> 5, f = idx & 31;
        bufA[f * 257 + t] = xb[idx];
    }
    __syncthreads();

    float* bin  = bufA;
    float* bout = bufB;
    const int o  = tid & 31;
    const int t0 = (tid >> 5) * 32;

    for (int layer = 0; layer < 3; ++layer) {
        const float* Wg = (layer == 0) ? cw1 : ((layer == 1) ? cw2 : cw3);
        const float* Bg = (layer == 0) ? cb1 : ((layer == 1) ? cb2 : cb3);
        for (int idx = tid; idx < 32 * 96; idx += 256) {
            int oo = idx / 96, rem = idx - oo * 96;
            sW[oo * 97 + rem] = Wg[idx];
        }
        if (tid < 32) sB[tid] = Bg[tid];
        __syncthreads();

        float acc[32];
        const float bias = sB[o];
        #pragma unroll
        for (int tt = 0; tt < 32; ++tt) acc[tt] = bias;

        for (int i = 0; i < 32; ++i) {
            const float w0 = sW[o * 97 + i * 3 + 0];
            const float w1 = sW[o * 97 + i * 3 + 1];
            const float w2 = sW[o * 97 + i * 3 + 2];
            const float* row = bin + i * 257;
            float vm = (t0 == 0) ? 0.0f : row[t0 - 1];
            float v0 = row[t0];
            #pragma unroll
            for (int tt = 0; tt < 32; ++tt) {
                float vp = (t0 + tt == 255) ? 0.0f : row[t0 + tt + 1];
                acc[tt] = fmaf(w0, vm, acc[tt]);
                acc[tt] = fmaf(w1, v0, acc[tt]);
                acc[tt] = fmaf(w2, vp, acc[tt]);
                vm = v0; v0 = vp;
            }
        }
        #pragma unroll
        for (int tt = 0; tt < 32; ++tt)
            bout[o * 257 + t0 + tt] = fmaxf(acc[tt], 0.0f);
        __syncthreads();
        float* tmp = bin; bin = bout; bout = tmp;
    }

    float* og = out + (size_t)b * T_LEN * NCH;
    #pragma unroll
    for (int c = 0; c < 32; ++c) {
        int idx = c * 256 + tid;
        int t = idx >> 5, f = idx & 31;
        og[idx] = bin[f * 257 + t];
    }
}

// ---------------- recurrent scan: 1 batch row per wave ----------------
__global__ __launch_bounds__(256) void scan_kernel(
    const float* __restrict__ tcn,
    const float* __restrict__ W_ih, const float* __restrict__ W_hh,
    const float* __restrict__ b_ih, const float* __restrict__ b_hh,
    const float* __restrict__ qw,
    const float* __restrict__ Wq, const float* __restrict__ bq,
    const float* __restrict__ Wo, const float* __restrict__ bo,
    float* __restrict__ out)
{
    // sW[g][0..31]=W_ih[g], [32..63]=W_hh[g]; pad to 68 floats (16B-aligned rows)
    __shared__ __align__(16) float sW[128 * 68];
    __shared__ __align__(16) float sxc[4][64];   // per wave: [0..31]=x_t, [32..63]=h

    const int tid = threadIdx.x;
    for (int idx = tid; idx < 128 * 64; idx += 256) {
        int g = idx >> 6, k = idx & 63;
        sW[g * 68 + k] = (k < 32) ? W_ih[g * 32 + k] : W_hh[g * 32 + (k - 32)];
    }
    __syncthreads();

    const int w    = tid >> 6;
    const int lane = tid & 63;
    const int b    = blockIdx.x * 4 + w;
    const float* xrow = tcn + (size_t)b * T_LEN * NCH;
    float* xc = sxc[w];

    const float bias0 = b_ih[lane] + b_hh[lane];
    const float bias1 = b_ih[lane + 64] + b_hh[lane + 64];

    // variational RY half-angle trig, stashed ACROSS LANES: lane j<18 holds pair j
    float vs_s, vs_c;
    {
        int j = (lane < 18) ? lane : 0;
        fast_sincos(0.5f * qw[j], vs_s, vs_c);
    }

    // CNOT-ring permutation source index (composition of 6 CNOTs, GF(2)-linear)
    int psrc = lane;
    psrc ^= (psrc & 1) << 5;
    psrc ^= (psrc & 2) >> 1;
    psrc ^= (psrc & 4) >> 1;
    psrc ^= (psrc & 8) >> 1;
    psrc ^= (psrc & 16) >> 1;
    psrc ^= (psrc & 32) >> 1;

    float wqr[6], bqr = 0.0f, wor = 0.0f;
    #pragma unroll
    for (int k = 0; k < 6; ++k) wqr[k] = 0.0f;
    if (lane < 32) {
        #pragma unroll
        for (int k = 0; k < 6; ++k) wqr[k] = Wq[lane * 6 + k];
        bqr = bq[lane];
        wor = Wo[lane];
    }

    const float4* xq  = (const float4*)xc;
    const float4* w0q = (const float4*)(sW + lane * 68);
    const float4* w1q = (const float4*)(sW + (lane + 64) * 68);

    float hh = 0.0f, cx = 0.0f;
    float xpre = (lane < 32) ? xrow[lane] : 0.0f;

    for (int t = 0; t < T_LEN; ++t) {
        if (lane < 32) {
            xc[lane]      = xpre;   // x_t
            xc[32 + lane] = hh;     // h_{t-1}
        }
        float xnext = (lane < 32 && t < T_LEN - 1) ? xrow[(t + 1) * 32 + lane] : 0.0f;

        // gates: acc0 = gates[lane] (i|f), acc1 = gates[lane+64] (g|o)
        float a0 = bias0, a1 = bias1, b0 = 0.0f, b1 = 0.0f;
        #pragma unroll
        for (int kc = 0; kc < 16; kc += 2) {
            float4 xv = xq[kc];
            float4 u0 = w0q[kc];
            float4 u1 = w1q[kc];
            a0 = fmaf(u0.x, xv.x, a0); a0 = fmaf(u0.y, xv.y, a0);
            a0 = fmaf(u0.z, xv.z, a0); a0 = fmaf(u0.w, xv.w, a0);
            a1 = fmaf(u1.x, xv.x, a1); a1 = fmaf(u1.y, xv.y, a1);
            a1 = fmaf(u1.z, xv.z, a1); a1 = fmaf(u1.w, xv.w, a1);
            float4 xv2 = xq[kc + 1];
            float4 v0  = w0q[kc + 1];
            float4 v1  = w1q[kc + 1];
            b0 = fmaf(v0.x, xv2.x, b0); b0 = fmaf(v0.y, xv2.y, b0);
            b0 = fmaf(v0.z, xv2.z, b0); b0 = fmaf(v0.w, xv2.w, b0);
            b1 = fmaf(v1.x, xv2.x, b1); b1 = fmaf(v1.y, xv2.y, b1);
            b1 = fmaf(v1.z, xv2.z, b1); b1 = fmaf(v1.w, xv2.w, b1);
        }
        float acc0 = a0 + b0, acc1 = a1 + b1;

        float fg = __shfl_xor(acc0, 32, 64);
        float og = __shfl_xor(acc1, 32, 64);
        float c  = sigf(fg) * cx + sigf(acc0) * tanhf(acc1);
        float h  = sigf(og) * tanhf(c);
        h = 3.99f * h * (1.0f - h);                        // logistic map
        float h0 = rdlane(h, 0);
        float h1 = rdlane(h, 1);
        if (lane == 0)      h = 1.0f - 1.4f * h0 * h0 + h1; // henon
        else if (lane == 1) h = 0.3f * h0;
        cx = c;

        // each lane sincos's its OWN h; gather the 6 needed pairs via readlane
        float s_own, c_own;
        fast_sincos(0.5f * h, s_own, c_own);
        float sa[6], ca[6];
        #pragma unroll
        for (int i = 0; i < 6; ++i) { sa[i] = rdlane(s_own, i); ca[i] = rdlane(c_own, i); }

        // encoding acts on |0..0>: product state, amp[l] = prod_i (U_i|0>)[bit_i(l)]
        float re = 1.0f, im = 0.0f;
        #pragma unroll
        for (int i = 0; i < 6; ++i) {
            const int jy = (i + 1) % 6, jz = (i + 2) % 6;
            float A = ca[jy] * ca[i], Bv = sa[jy] * sa[i];
            float C = sa[jy] * ca[i], D = ca[jy] * sa[i];
            float ur = fmaf(Bv, sa[jz], A * ca[jz]);     // Re m00
            float ui = fmaf(Bv, ca[jz], -(A * sa[jz]));  // Im m00
            float pr = fmaf(D, sa[jz], C * ca[jz]);      // Re m10
            float pi = fmaf(C, sa[jz], -(D * ca[jz]));   // Im m10
            const bool hi = (lane & (32 >> i)) != 0;
            float gr = hi ? pr : ur;
            float gi = hi ? pi : ui;
            float nr = fmaf(re, gr, -(im * gi));
            float ni = fmaf(re, gi, im * gr);
            re = nr; im = ni;
        }

        // 3 variational layers: 6x RY + one bpermute for the CNOT ring
        #pragma unroll
        for (int l = 0; l < 3; ++l) {
            #pragma unroll
            for (int q = 0; q < 6; ++q) {
                const int m = 32 >> q;
                float cc  = rdlane(vs_c, l * 6 + q);
                float ss0 = rdlane(vs_s, l * 6 + q);
                float pre = (m == 1) ? xor1f(re) : ((m == 2) ? xor2f(re) : __shfl_xor(re, m, 64));
                float pim = (m == 1) ? xor1f(im) : ((m == 2) ? xor2f(im) : __shfl_xor(im, m, 64));
                float ss = (lane & m) ? ss0 : -ss0;
                re = fmaf(ss, pre, cc * re);
                im = fmaf(ss, pim, cc * im);
            }
            re = __shfl(re, psrc, 64);
            im = __shfl(im, psrc, 64);
        }

        // probs -> all 6 <Z_i> via Walsh-Hadamard butterfly
        float p = re * re + im * im;
        #pragma unroll
        for (int st = 0; st < 6; ++st) {
            const int m = 1 << st;
            float pp = (m == 1) ? xor1f(p) : ((m == 2) ? xor2f(p) : __shfl_xor(p, m, 64));
            p = (lane & m) ? (pp - p) : (p + pp);
        }
        float upd = bqr;
        #pragma unroll
        for (int k = 0; k < 6; ++k) {
            float ev = rdlane(p, 32 >> k);   // <Z_k> sits at lane 2^(5-k)
            upd = fmaf(ev, wqr[k], upd);
        }
        hh = h + upd;
        xpre = xnext;
    }

    float contrib = (lane < 32) ? hh * wor : 0.0f;
    #pragma unroll
    for (int off = 32; off >= 1; off >>= 1)
        contrib += __shfl_xor(contrib, off, 64);
    if (lane == 0) out[b] = sigf(contrib + bo[0]);
}

extern "C" void kernel_launch(void* const* d_in, const int* in_sizes, int n_in,
                              void* d_out, int out_size, void* d_ws, size_t ws_size,
                              hipStream_t stream)
{
    const float* x    = (const float*)d_in[0];
    const float* cw1  = (const float*)d_in[1];
    const float* cb1  = (const float*)d_in[2];
    const float* cw2  = (const float*)d_in[3];
    const float* cb2  = (const float*)d_in[4];
    const float* cw3  = (const float*)d_in[5];
    const float* cb3  = (const float*)d_in[6];
    const float* W_ih = (const float*)d_in[7];
    const float* W_hh = (const float*)d_in[8];
    const float* b_ih = (const float*)d_in[9];
    const float* b_hh = (const float*)d_in[10];
    const float* qw   = (const float*)d_in[11];
    const float* Wq   = (const float*)d_in[12];
    const float* bq   = (const float*)d_in[13];
    const float* Wo   = (const float*)d_in[14];
    const float* bo   = (const float*)d_in[15];

    float* tcn = (float*)d_ws;  // [4096][256][32] f32 = 128 MiB scratch

    hipLaunchKernelGGL(tcn_kernel, dim3(B_TOT), dim3(256), 0, stream,
                       x, cw1, cb1, cw2, cb2, cw3, cb3, tcn);
    hipLaunchKernelGGL(scan_kernel, dim3(B_TOT / 4), dim3(256), 0, stream,
                       tcn, W_ih, W_hh, b_ih, b_hh, qw, Wq, bq, Wo, bo,
                       (float*)d_out);
}

// Round 4
// 1271.073 us; speedup vs baseline: 3.4557x; 1.2265x over previous
//
#include <hip/hip_runtime.h>

#define B_TOT 4096
#define T_LEN 256
#define NCH   32

typedef float f2 __attribute__((ext_vector_type(2)));
typedef float f4 __attribute__((ext_vector_type(4)));

__device__ __forceinline__ float rdlane(float v, int l) {
    return __int_as_float(__builtin_amdgcn_readlane(__float_as_int(v), l));
}
__device__ __forceinline__ float xor1f(float x) {
    return __int_as_float(__builtin_amdgcn_mov_dpp(__float_as_int(x), 0xB1, 0xF, 0xF, true));
}
__device__ __forceinline__ float xor2f(float x) {
    return __int_as_float(__builtin_amdgcn_mov_dpp(__float_as_int(x), 0x4E, 0xF, 0xF, true));
}
__device__ __forceinline__ float xsign(float x, unsigned m) {
    return __int_as_float(__float_as_int(x) ^ (int)m);
}
// native-exp sigmoid / tanh (v_exp_f32 + v_rcp_f32, ~1-2 ulp)
__device__ __forceinline__ float fast_sig(float x) {
    return __builtin_amdgcn_rcpf(1.0f + __expf(-x));
}
__device__ __forceinline__ float fast_tanh(float x) {
    return fmaf(-2.0f, __builtin_amdgcn_rcpf(__expf(2.0f * x) + 1.0f), 1.0f);
}

// sin/cos via Cody-Waite pi-reduction + Taylor (deg 11/12). abs err ~1e-7.
__device__ __forceinline__ void fast_sincos(float x, float& s, float& c) {
    float k = rintf(x * 0.3183098861837907f);
    float r = fmaf(-k, 3.14159274101257324f, x);
    r = fmaf(-k, -8.74227765734758577e-8f, r);
    float r2 = r * r;
    float sp = -2.50521084e-8f;
    sp = fmaf(sp, r2, 2.75573192e-6f);
    sp = fmaf(sp, r2, -1.98412698e-4f);
    sp = fmaf(sp, r2, 8.33333333e-3f);
    sp = fmaf(sp, r2, -1.66666667e-1f);
    float sv = fmaf(sp * r2, r, r);
    float cp = 2.08767570e-9f;
    cp = fmaf(cp, r2, -2.75573192e-7f);
    cp = fmaf(cp, r2, 2.48015873e-5f);
    cp = fmaf(cp, r2, -1.38888889e-3f);
    cp = fmaf(cp, r2, 4.16666667e-2f);
    cp = fmaf(cp, r2, -0.5f);
    float cv = fmaf(cp, r2, 1.0f);
    float sgn = ((int)k & 1) ? -1.0f : 1.0f;
    s = sv * sgn;
    c = cv * sgn;
}

// ---------------- TCN: 3x (conv1d k=3 'same' + bias + ReLU) ----------------
__global__ __launch_bounds__(256) void tcn_kernel(
    const float* __restrict__ x,
    const float* __restrict__ cw1, const float* __restrict__ cb1,
    const float* __restrict__ cw2, const float* __restrict__ cb2,
    const float* __restrict__ cw3, const float* __restrict__ cb3,
    float* __restrict__ out)
{
    __shared__ float bufA[NCH * 257];
    __shared__ float bufB[NCH * 257];
    __shared__ float sW[NCH * 97];
    __shared__ float sB[NCH];

    const int b   = blockIdx.x;
    const int tid = threadIdx.x;
    const float* xb = x + (size_t)b * T_LEN * NCH;

    #pragma unroll
    for (int c = 0; c < 32; ++c) {
        int idx = c * 256 + tid;
        int t = idx >> 5, f = idx & 31;
        bufA[f * 257 + t] = xb[idx];
    }
    __syncthreads();

    float* bin  = bufA;
    float* bout = bufB;
    const int o  = tid & 31;
    const int t0 = (tid >> 5) * 32;

    for (int layer = 0; layer < 3; ++layer) {
        const float* Wg = (layer == 0) ? cw1 : ((layer == 1) ? cw2 : cw3);
        const float* Bg = (layer == 0) ? cb1 : ((layer == 1) ? cb2 : cb3);
        for (int idx = tid; idx < 32 * 96; idx += 256) {
            int oo = idx / 96, rem = idx - oo * 96;
            sW[oo * 97 + rem] = Wg[idx];
        }
        if (tid < 32) sB[tid] = Bg[tid];
        __syncthreads();

        float acc[32];
        const float bias = sB[o];
        #pragma unroll
        for (int tt = 0; tt < 32; ++tt) acc[tt] = bias;

        for (int i = 0; i < 32; ++i) {
            const float w0 = sW[o * 97 + i * 3 + 0];
            const float w1 = sW[o * 97 + i * 3 + 1];
            const float w2 = sW[o * 97 + i * 3 + 2];
            const float* row = bin + i * 257;
            float vm = (t0 == 0) ? 0.0f : row[t0 - 1];
            float v0 = row[t0];
            #pragma unroll
            for (int tt = 0; tt < 32; ++tt) {
                float vp = (t0 + tt == 255) ? 0.0f : row[t0 + tt + 1];
                acc[tt] = fmaf(w0, vm, acc[tt]);
                acc[tt] = fmaf(w1, v0, acc[tt]);
                acc[tt] = fmaf(w2, vp, acc[tt]);
                vm = v0; v0 = vp;
            }
        }
        #pragma unroll
        for (int tt = 0; tt < 32; ++tt)
            bout[o * 257 + t0 + tt] = fmaxf(acc[tt], 0.0f);
        __syncthreads();
        float* tmp = bin; bin = bout; bout = tmp;
    }

    float* og = out + (size_t)b * T_LEN * NCH;
    #pragma unroll
    for (int c = 0; c < 32; ++c) {
        int idx = c * 256 + tid;
        int t = idx >> 5, f = idx & 31;
        og[idx] = bin[f * 257 + t];
    }
}

// ---------------- recurrent scan: 1 batch row per wave ----------------
__global__ __launch_bounds__(256) void scan_kernel(
    const float* __restrict__ tcn,
    const float* __restrict__ W_ih, const float* __restrict__ W_hh,
    const float* __restrict__ b_ih, const float* __restrict__ b_hh,
    const float* __restrict__ qw,
    const float* __restrict__ Wq, const float* __restrict__ bq,
    const float* __restrict__ Wo, const float* __restrict__ bo,
    float* __restrict__ out)
{
    // sW row g, interleaved k-pairs: [2k]=W_ih[g][k], [2k+1]=W_hh[g][k]; pad 68
    __shared__ __align__(16) float sW[128 * 68];
    __shared__ __align__(16) float sxc[4][64];   // per wave, interleaved: [2k]=x_t[k], [2k+1]=h[k]

    const int tid = threadIdx.x;
    for (int idx = tid; idx < 128 * 64; idx += 256) {
        int g = idx >> 6, k2 = idx & 63, k = k2 >> 1;
        sW[g * 68 + k2] = (k2 & 1) ? W_hh[g * 32 + k] : W_ih[g * 32 + k];
    }
    __syncthreads();

    const int w    = tid >> 6;
    const int lane = tid & 63;
    const int b    = blockIdx.x * 4 + w;
    const float* xrow = tcn + (size_t)b * T_LEN * NCH;
    float* xc = sxc[w];

    const float bias0 = b_ih[lane] + b_hh[lane];
    const float bias1 = b_ih[lane + 64] + b_hh[lane + 64];

    // variational RY half-angle trig -> 36 uniform scalars (hoisted, one-time readlanes)
    float ccu[18], ssu[18];
    {
        float s0, c0;
        int j = (lane < 18) ? lane : 0;
        fast_sincos(0.5f * qw[j], s0, c0);
        #pragma unroll
        for (int i = 0; i < 18; ++i) { ssu[i] = rdlane(s0, i); ccu[i] = rdlane(c0, i); }
    }

    // per-lane sign masks: nm[q] = (lane & 32>>q) ? 0 : 0x80000000
    unsigned nm[6];
    #pragma unroll
    for (int q = 0; q < 6; ++q) nm[q] = (lane & (32 >> q)) ? 0u : 0x80000000u;

    // CNOT-ring permutation source index (GF(2)-linear composition)
    int psrc = lane;
    psrc ^= (psrc & 1) << 5;
    psrc ^= (psrc & 2) >> 1;
    psrc ^= (psrc & 4) >> 1;
    psrc ^= (psrc & 8) >> 1;
    psrc ^= (psrc & 16) >> 1;
    psrc ^= (psrc & 32) >> 1;

    // cyclic-6 rotation patterns for encoding-matrix build
    const int r1 = (lane + 1) % 6;
    const int r2 = (lane + 2) % 6;

    float wqr[6], bqr = 0.0f, wor = 0.0f;
    #pragma unroll
    for (int k = 0; k < 6; ++k) wqr[k] = 0.0f;
    if (lane < 32) {
        #pragma unroll
        for (int k = 0; k < 6; ++k) wqr[k] = Wq[lane * 6 + k];
        bqr = bq[lane];
        wor = Wo[lane];
    }

    const f4* xq  = (const f4*)xc;
    const f4* w0q = (const f4*)(sW + lane * 68);
    const f4* w1q = (const f4*)(sW + (lane + 64) * 68);

    float hh = 0.0f, cx = 0.0f;
    float xpre = (lane < 32) ? xrow[lane] : 0.0f;

    for (int t = 0; t < T_LEN; ++t) {
        if (lane < 32) {
            f2 xh2; xh2.x = xpre; xh2.y = hh;
            ((f2*)xc)[lane] = xh2;              // one ds_write_b64
        }
        float xnext = (lane < 32 && t < T_LEN - 1) ? xrow[(t + 1) * 32 + lane] : 0.0f;

        // gates via packed-f32 FMA on (x,h)-pairs; lo accumulates x-terms, hi h-terms
        f2 A0; A0.x = bias0; A0.y = 0.0f;
        f2 A1; A1.x = bias1; A1.y = 0.0f;
        f2 B0; B0.x = 0.0f;  B0.y = 0.0f;
        f2 B1; B1.x = 0.0f;  B1.y = 0.0f;
        #pragma unroll
        for (int kc = 0; kc < 16; ++kc) {
            f4 xv = xq[kc], u0 = w0q[kc], u1 = w1q[kc];
            f2 xlo = __builtin_shufflevector(xv, xv, 0, 1);
            f2 xhi = __builtin_shufflevector(xv, xv, 2, 3);
            A0 = __builtin_elementwise_fma(__builtin_shufflevector(u0, u0, 0, 1), xlo, A0);
            B0 = __builtin_elementwise_fma(__builtin_shufflevector(u0, u0, 2, 3), xhi, B0);
            A1 = __builtin_elementwise_fma(__builtin_shufflevector(u1, u1, 0, 1), xlo, A1);
            B1 = __builtin_elementwise_fma(__builtin_shufflevector(u1, u1, 2, 3), xhi, B1);
        }
        float acc0 = (A0.x + A0.y) + (B0.x + B0.y);
        float acc1 = (A1.x + A1.y) + (B1.x + B1.y);

        float fg = __shfl_xor(acc0, 32, 64);
        float og = __shfl_xor(acc1, 32, 64);
        float c  = fast_sig(fg) * cx + fast_sig(acc0) * fast_tanh(acc1);
        float h  = fast_sig(og) * fast_tanh(c);
        h = 3.99f * h * (1.0f - h);                         // logistic map
        float h0 = rdlane(h, 0);
        float h1 = rdlane(h, 1);
        float hen0 = fmaf(-1.4f * h0, h0, 1.0f) + h1;       // henon, branchless
        float hen1 = 0.3f * h0;
        h = (lane == 0) ? hen0 : h;
        h = (lane == 1) ? hen1 : h;
        cx = c;

        // per-lane sincos of own h; rotate by 1,2 among lanes 0-5 (bpermute)
        float s_own, c_own;
        fast_sincos(0.5f * h, s_own, c_own);
        float s1 = __shfl(s_own, r1, 64), c1 = __shfl(c_own, r1, 64);
        float s2 = __shfl(s_own, r2, 64), c2 = __shfl(c_own, r2, 64);

        // lane i builds wire-i fused U=RZ*RY*RX column-0 entries (valid on lanes 0-5)
        float A_ = c1 * c_own, Bv = s1 * s_own;
        float C_ = s1 * c_own, D_ = c1 * s_own;
        float ur_ = fmaf(Bv, s2,  A_ * c2);
        float ui_ = fmaf(Bv, c2, -(A_ * s2));
        float pr_ = fmaf(D_, s2,  C_ * c2);
        float pi_ = fmaf(C_, s2, -(D_ * c2));

        // product state: amp[l] = prod_i (bit_i ? (pr,pi) : (ur,ui))
        float re = 1.0f, im = 0.0f;
        #pragma unroll
        for (int i = 0; i < 6; ++i) {
            float ur = rdlane(ur_, i), ui = rdlane(ui_, i);
            float pr = rdlane(pr_, i), pi = rdlane(pi_, i);
            const bool hi = (lane & (32 >> i)) != 0;
            float gr = hi ? pr : ur;
            float gi = hi ? pi : ui;
            float nr = fmaf(re, gr, -(im * gi));
            float ni = fmaf(re, gi, im * gr);
            re = nr; im = ni;
        }

        // 3 variational layers: 6x RY (hoisted consts, xor-sign) + ring CNOT permute
        #pragma unroll
        for (int l = 0; l < 3; ++l) {
            #pragma unroll
            for (int q = 0; q < 6; ++q) {
                const int m = 32 >> q;
                float pre = (m == 1) ? xor1f(re) : ((m == 2) ? xor2f(re) : __shfl_xor(re, m, 64));
                float pim = (m == 1) ? xor1f(im) : ((m == 2) ? xor2f(im) : __shfl_xor(im, m, 64));
                float cc = ccu[l * 6 + q], ss = ssu[l * 6 + q];
                re = fmaf(ss, xsign(pre, nm[q]), cc * re);
                im = fmaf(ss, xsign(pim, nm[q]), cc * im);
            }
            re = __shfl(re, psrc, 64);
            im = __shfl(im, psrc, 64);
        }

        // probs -> all 6 <Z_i> via Walsh-Hadamard butterfly (xor-sign + sub)
        float p = fmaf(re, re, im * im);
        #pragma unroll
        for (int st = 0; st < 6; ++st) {
            const int m = 1 << st;
            float pp = (m == 1) ? xor1f(p) : ((m == 2) ? xor2f(p) : __shfl_xor(p, m, 64));
            p = pp - xsign(p, nm[5 - st]);
        }
        float upd = bqr;
        #pragma unroll
        for (int k = 0; k < 6; ++k) {
            float ev = rdlane(p, 32 >> k);
            upd = fmaf(ev, wqr[k], upd);
        }
        hh = h + upd;
        xpre = xnext;
    }

    float contrib = (lane < 32) ? hh * wor : 0.0f;
    #pragma unroll
    for (int off = 32; off >= 1; off >>= 1)
        contrib += __shfl_xor(contrib, off, 64);
    if (lane == 0) out[b] = fast_sig(contrib + bo[0]);
}

extern "C" void kernel_launch(void* const* d_in, const int* in_sizes, int n_in,
                              void* d_out, int out_size, void* d_ws, size_t ws_size,
                              hipStream_t stream)
{
    const float* x    = (const float*)d_in[0];
    const float* cw1  = (const float*)d_in[1];
    const float* cb1  = (const float*)d_in[2];
    const float* cw2  = (const float*)d_in[3];
    const float* cb2  = (const float*)d_in[4];
    const float* cw3  = (const float*)d_in[5];
    const float* cb3  = (const float*)d_in[6];
    const float* W_ih = (const float*)d_in[7];
    const float* W_hh = (const float*)d_in[8];
    const float* b_ih = (const float*)d_in[9];
    const float* b_hh = (const float*)d_in[10];
    const float* qw   = (const float*)d_in[11];
    const float* Wq   = (const float*)d_in[12];
    const float* bq   = (const float*)d_in[13];
    const float* Wo   = (const float*)d_in[14];
    const float* bo   = (const float*)d_in[15];

    float* tcn = (float*)d_ws;  // [4096][256][32] f32 = 128 MiB scratch

    hipLaunchKernelGGL(tcn_kernel, dim3(B_TOT), dim3(256), 0, stream,
                       x, cw1, cb1, cw2, cb2, cw3, cb3, tcn);
    hipLaunchKernelGGL(scan_kernel, dim3(B_TOT / 4), dim3(256), 0, stream,
                       tcn, W_ih, W_hh, b_ih, b_hh, qw, Wq, bq, Wo, bo,
                       (float*)d_out);
}

// Round 5
// 1112.757 us; speedup vs baseline: 3.9474x; 1.1423x over previous
//
#include <hip/hip_runtime.h>

#define B_TOT 4096
#define T_LEN 256
#define NCH   32

typedef float f2 __attribute__((ext_vector_type(2)));
typedef float f4 __attribute__((ext_vector_type(4)));

__device__ __forceinline__ float rdlane(float v, int l) {
    return __int_as_float(__builtin_amdgcn_readlane(__float_as_int(v), l));
}
__device__ __forceinline__ float xor1f(float x) {
    return __int_as_float(__builtin_amdgcn_mov_dpp(__float_as_int(x), 0xB1, 0xF, 0xF, true));
}
__device__ __forceinline__ float xor2f(float x) {
    return __int_as_float(__builtin_amdgcn_mov_dpp(__float_as_int(x), 0x4E, 0xF, 0xF, true));
}
__device__ __forceinline__ float xor3f(float x) {
    return __int_as_float(__builtin_amdgcn_mov_dpp(__float_as_int(x), 0x1B, 0xF, 0xF, true));
}
__device__ __forceinline__ float xsign(float x, unsigned m) {
    return __int_as_float(__float_as_int(x) ^ (int)m);
}
__device__ __forceinline__ float fast_sig(float x) {
    return __builtin_amdgcn_rcpf(1.0f + __expf(-x));
}
__device__ __forceinline__ float fast_tanh(float x) {
    return fmaf(-2.0f, __builtin_amdgcn_rcpf(__expf(2.0f * x) + 1.0f), 1.0f);
}

// full-range sincos (logistic/henon excursions can push |angle| to ~50)
__device__ __forceinline__ void fast_sincos(float x, float& s, float& c) {
    float k = rintf(x * 0.3183098861837907f);
    float r = fmaf(-k, 3.14159274101257324f, x);
    r = fmaf(-k, -8.74227765734758577e-8f, r);
    float r2 = r * r;
    float sp = -2.50521084e-8f;
    sp = fmaf(sp, r2, 2.75573192e-6f);
    sp = fmaf(sp, r2, -1.98412698e-4f);
    sp = fmaf(sp, r2, 8.33333333e-3f);
    sp = fmaf(sp, r2, -1.66666667e-1f);
    float sv = fmaf(sp * r2, r, r);
    float cp = 2.08767570e-9f;
    cp = fmaf(cp, r2, -2.75573192e-7f);
    cp = fmaf(cp, r2, 2.48015873e-5f);
    cp = fmaf(cp, r2, -1.38888889e-3f);
    cp = fmaf(cp, r2, 4.16666667e-2f);
    cp = fmaf(cp, r2, -0.5f);
    float cv = fmaf(cp, r2, 1.0f);
    float sgn = ((int)k & 1) ? -1.0f : 1.0f;
    s = sv * sgn;
    c = cv * sgn;
}

// ---------------- TCN: 3x (conv1d k=3 'same' + bias + ReLU) ----------------
__global__ __launch_bounds__(256) void tcn_kernel(
    const float* __restrict__ x,
    const float* __restrict__ cw1, const float* __restrict__ cb1,
    const float* __restrict__ cw2, const float* __restrict__ cb2,
    const float* __restrict__ cw3, const float* __restrict__ cb3,
    float* __restrict__ out)
{
    __shared__ float bufA[NCH * 257];
    __shared__ float bufB[NCH * 257];
    __shared__ float sW[NCH * 97];
    __shared__ float sB[NCH];

    const int b   = blockIdx.x;
    const int tid = threadIdx.x;
    const float* xb = x + (size_t)b * T_LEN * NCH;

    #pragma unroll
    for (int c = 0; c < 32; ++c) {
        int idx = c * 256 + tid;
        int t = idx >> 5, f = idx & 31;
        bufA[f * 257 + t] = xb[idx];
    }
    __syncthreads();

    float* bin  = bufA;
    float* bout = bufB;
    const int o  = tid & 31;
    const int t0 = (tid >> 5) * 32;

    for (int layer = 0; layer < 3; ++layer) {
        const float* Wg = (layer == 0) ? cw1 : ((layer == 1) ? cw2 : cw3);
        const float* Bg = (layer == 0) ? cb1 : ((layer == 1) ? cb2 : cb3);
        for (int idx = tid; idx < 32 * 96; idx += 256) {
            int oo = idx / 96, rem = idx - oo * 96;
            sW[oo * 97 + rem] = Wg[idx];
        }
        if (tid < 32) sB[tid] = Bg[tid];
        __syncthreads();

        float acc[32];
        const float bias = sB[o];
        #pragma unroll
        for (int tt = 0; tt < 32; ++tt) acc[tt] = bias;

        for (int i = 0; i < 32; ++i) {
            const float w0 = sW[o * 97 + i * 3 + 0];
            const float w1 = sW[o * 97 + i * 3 + 1];
            const float w2 = sW[o * 97 + i * 3 + 2];
            const float* row = bin + i * 257;
            float vm = (t0 == 0) ? 0.0f : row[t0 - 1];
            float v0 = row[t0];
            #pragma unroll
            for (int tt = 0; tt < 32; ++tt) {
                float vp = (t0 + tt == 255) ? 0.0f : row[t0 + tt + 1];
                acc[tt] = fmaf(w0, vm, acc[tt]);
                acc[tt] = fmaf(w1, v0, acc[tt]);
                acc[tt] = fmaf(w2, vp, acc[tt]);
                vm = v0; v0 = vp;
            }
        }
        #pragma unroll
        for (int tt = 0; tt < 32; ++tt)
            bout[o * 257 + t0 + tt] = fmaxf(acc[tt], 0.0f);
        __syncthreads();
        float* tmp = bin; bin = bout; bout = tmp;
    }

    float* og = out + (size_t)b * T_LEN * NCH;
    #pragma unroll
    for (int c = 0; c < 32; ++c) {
        int idx = c * 256 + tid;
        int t = idx >> 5, f = idx & 31;
        og[idx] = bin[f * 257 + t];
    }
}

// ---------------- recurrent scan: 1 batch row per 64-thread block ----------
// Weights live in VGPRs (rows lane & lane+64 as packed f2); LDS only stages
// (x_t,h) broadcasts + the 6 encoding columns. CNOT ring permutations are
// DEFERRED into gate masks (P is GF(2)-linear):
//   P: b32'=b32^b1; b16'=b16^b32^b1; b8'=b8^b16; b4'=b4^b8; b2'=b2^b4; b1'=b1^b2
//   layer2 partner = P(m)   = {48,24,12,6,3,49},  hi-sign mask = P^-T(m)  = {31,48,56,60,62,63}
//   layer3 partner = P^2(m) = {40,20,10,5,50,25}, hi-sign mask = P^-2T(m) = {53,47,23,43,21,42}
//   readout lane for <Z_q>  = P^-3T(32>>q)        = {44,26,13,38,51,25}
// Layer-1 RYs are folded into the encoding columns (both pre-entanglement).
__global__ __launch_bounds__(64) void scan_kernel(
    const float* __restrict__ tcn,
    const float* __restrict__ W_ih, const float* __restrict__ W_hh,
    const float* __restrict__ b_ih, const float* __restrict__ b_hh,
    const float* __restrict__ qw,
    const float* __restrict__ Wq, const float* __restrict__ bq,
    const float* __restrict__ Wo, const float* __restrict__ bo,
    float* __restrict__ out)
{
    __shared__ __align__(16) float xc2[64];   // (x_k,h_k) pairs, k<32
    __shared__ __align__(16) float colb[24];  // 6 wires x (ur,ui,pr,pi)

    const int lane = threadIdx.x;
    const int b    = blockIdx.x;
    const float* xrow = tcn + (size_t)b * T_LEN * NCH;

    // ---- one-time: weights into VGPRs, packed (row lane, row lane+64) ----
    f2 wih[32], whh[32];
    #pragma unroll
    for (int k = 0; k < 32; ++k) {
        wih[k] = f2{ W_ih[lane * 32 + k], W_ih[(lane + 64) * 32 + k] };
        whh[k] = f2{ W_hh[lane * 32 + k], W_hh[(lane + 64) * 32 + k] };
    }
    const f2 bias01 = f2{ b_ih[lane] + b_hh[lane],
                          b_ih[lane + 64] + b_hh[lane + 64] };

    // ---- one-time: variational trig (uniform scalars) ----
    float ssu[18], ccu[18];
    {
        float s0, c0;
        int j = (lane < 18) ? lane : 0;
        fast_sincos(0.5f * qw[j], s0, c0);
        #pragma unroll
        for (int i = 0; i < 18; ++i) { ssu[i] = rdlane(s0, i); ccu[i] = rdlane(c0, i); }
    }
    // per-lane layer-1 coeffs (wire = lane; valid lanes 0-5)
    float vs1 = ssu[0], vc1 = ccu[0];
    #pragma unroll
    for (int i = 1; i < 6; ++i) {
        vs1 = (lane == i) ? ssu[i] : vs1;
        vc1 = (lane == i) ? ccu[i] : vc1;
    }
    // layer-2/3 per-lane pre-signed sines (sign = parity(lane & mu))
    const int MU2[6] = {31, 48, 56, 60, 62, 63};
    const int MU3[6] = {53, 47, 23, 43, 21, 42};
    float ssl2[6], ssl3[6], cc2[6], cc3[6];
    #pragma unroll
    for (int q = 0; q < 6; ++q) {
        ssl2[q] = (__popc(lane & MU2[q]) & 1) ? ssu[6 + q]  : -ssu[6 + q];
        ssl3[q] = (__popc(lane & MU3[q]) & 1) ? ssu[12 + q] : -ssu[12 + q];
        cc2[q] = ccu[6 + q];
        cc3[q] = ccu[12 + q];
    }
    // WH butterfly sign masks
    unsigned nm[6];
    #pragma unroll
    for (int q = 0; q < 6; ++q) nm[q] = (lane & (32 >> q)) ? 0u : 0x80000000u;
    // product-state read indices (f2 units into colb)
    int cidx[6];
    #pragma unroll
    for (int i = 0; i < 6; ++i) cidx[i] = i * 2 + ((lane & (32 >> i)) ? 1 : 0);
    // encoding gather sources (wires lane+1, lane+2 mod 6)
    const int r1 = (lane + 1) % 6, r2 = (lane + 2) % 6;

    float wqr[6] = {0, 0, 0, 0, 0, 0};
    float bqr = 0.0f, wor = 0.0f;
    if (lane < 32) {
        #pragma unroll
        for (int k = 0; k < 6; ++k) wqr[k] = Wq[lane * 6 + k];
        bqr = bq[lane];
        wor = Wo[lane];
    }

    float hh = 0.0f, cxs = 0.0f;
    float xpre = (lane < 32) ? xrow[lane] : 0.0f;
    const f4* xcq  = (const f4*)xc2;
    const f2* colq = (const f2*)colb;

    for (int t = 0; t < T_LEN; ++t) {
        if (lane < 32) ((f2*)xc2)[lane] = f2{xpre, hh};
        float xnext = (lane < 32 && t < T_LEN - 1) ? xrow[(t + 1) * 32 + lane] : 0.0f;

        // ---- gates: acc.x = gates[lane], acc.y = gates[lane+64] ----
        f2 acc = bias01, accb = f2{0.0f, 0.0f};
        #pragma unroll
        for (int j = 0; j < 16; ++j) {
            f4 v = xcq[j];   // (x_{2j}, h_{2j}, x_{2j+1}, h_{2j+1}) broadcast
            acc  = __builtin_elementwise_fma(wih[2 * j],     __builtin_shufflevector(v, v, 0, 0), acc);
            acc  = __builtin_elementwise_fma(whh[2 * j],     __builtin_shufflevector(v, v, 1, 1), acc);
            accb = __builtin_elementwise_fma(wih[2 * j + 1], __builtin_shufflevector(v, v, 2, 2), accb);
            accb = __builtin_elementwise_fma(whh[2 * j + 1], __builtin_shufflevector(v, v, 3, 3), accb);
        }
        acc += accb;
        float acc0 = acc.x, acc1 = acc.y;

        float fg = __shfl_xor(acc0, 32, 64);
        float og = __shfl_xor(acc1, 32, 64);
        float c  = fast_sig(fg) * cxs + fast_sig(acc0) * fast_tanh(acc1);
        float h  = fast_sig(og) * fast_tanh(c);
        h = 3.99f * h * (1.0f - h);                       // logistic map
        float h0 = rdlane(h, 0), h1 = rdlane(h, 1);
        float hen0 = fmaf(-1.4f * h0, h0, 1.0f) + h1;     // henon
        float hen1 = 0.3f * h0;
        h = (lane == 0) ? hen0 : h;
        h = (lane == 1) ? hen1 : h;
        cxs = c;

        // ---- encoding columns (fused RZ*RY*RX |0>, + layer-1 RY fold) ----
        float s_own, c_own;
        fast_sincos(0.5f * h, s_own, c_own);
        float s1v = __shfl(s_own, r1, 64), c1v = __shfl(c_own, r1, 64);
        float s2v = __shfl(s_own, r2, 64), c2v = __shfl(c_own, r2, 64);
        float A_ = c1v * c_own, Bv = s1v * s_own;
        float C_ = s1v * c_own, D_ = c1v * s_own;
        float ur = fmaf(Bv, s2v,  A_ * c2v);
        float ui = fmaf(Bv, c2v, -(A_ * s2v));
        float pr = fmaf(D_, s2v,  C_ * c2v);
        float pi = fmaf(C_, s2v, -(D_ * c2v));
        float nur = fmaf(vc1, ur, -(vs1 * pr));
        float nui = fmaf(vc1, ui, -(vs1 * pi));
        float npr = fmaf(vs1, ur,  vc1 * pr);
        float npi = fmaf(vs1, ui,  vc1 * pi);
        if (lane < 6) *(f4*)&colb[lane * 4] = f4{nur, nui, npr, npi};

        // ---- product state: amp[lane] = prod_i col_i[bit_i(lane)] ----
        f2 g0 = colq[cidx[0]];
        float re = g0.x, im = g0.y;
        #pragma unroll
        for (int i = 1; i < 6; ++i) {
            f2 g = colq[cidx[i]];
            float nr = fmaf(re, g.x, -(im * g.y));
            float ni = fmaf(re, g.y,   im * g.x);
            re = nr; im = ni;
        }

        // ---- layer 2 RYs (deferred-CNOT masks) ----
        {
            float pre, pim;
            pre = __shfl_xor(re, 48, 64); pim = __shfl_xor(im, 48, 64);
            re = fmaf(ssl2[0], pre, cc2[0] * re); im = fmaf(ssl2[0], pim, cc2[0] * im);
            pre = __shfl_xor(re, 24, 64); pim = __shfl_xor(im, 24, 64);
            re = fmaf(ssl2[1], pre, cc2[1] * re); im = fmaf(ssl2[1], pim, cc2[1] * im);
            pre = __shfl_xor(re, 12, 64); pim = __shfl_xor(im, 12, 64);
            re = fmaf(ssl2[2], pre, cc2[2] * re); im = fmaf(ssl2[2], pim, cc2[2] * im);
            pre = __shfl_xor(re, 6, 64);  pim = __shfl_xor(im, 6, 64);
            re = fmaf(ssl2[3], pre, cc2[3] * re); im = fmaf(ssl2[3], pim, cc2[3] * im);
            pre = xor3f(re);              pim = xor3f(im);
            re = fmaf(ssl2[4], pre, cc2[4] * re); im = fmaf(ssl2[4], pim, cc2[4] * im);
            pre = __shfl_xor(re, 49, 64); pim = __shfl_xor(im, 49, 64);
            re = fmaf(ssl2[5], pre, cc2[5] * re); im = fmaf(ssl2[5], pim, cc2[5] * im);
        }
        // ---- layer 3 RYs ----
        {
            float pre, pim;
            pre = __shfl_xor(re, 40, 64); pim = __shfl_xor(im, 40, 64);
            re = fmaf(ssl3[0], pre, cc3[0] * re); im = fmaf(ssl3[0], pim, cc3[0] * im);
            pre = __shfl_xor(re, 20, 64); pim = __shfl_xor(im, 20, 64);
            re = fmaf(ssl3[1], pre, cc3[1] * re); im = fmaf(ssl3[1], pim, cc3[1] * im);
            pre = __shfl_xor(re, 10, 64); pim = __shfl_xor(im, 10, 64);
            re = fmaf(ssl3[2], pre, cc3[2] * re); im = fmaf(ssl3[2], pim, cc3[2] * im);
            pre = __shfl_xor(re, 5, 64);  pim = __shfl_xor(im, 5, 64);
            re = fmaf(ssl3[3], pre, cc3[3] * re); im = fmaf(ssl3[3], pim, cc3[3] * im);
            pre = __shfl_xor(re, 50, 64); pim = __shfl_xor(im, 50, 64);
            re = fmaf(ssl3[4], pre, cc3[4] * re); im = fmaf(ssl3[4], pim, cc3[4] * im);
            pre = __shfl_xor(re, 25, 64); pim = __shfl_xor(im, 25, 64);
            re = fmaf(ssl3[5], pre, cc3[5] * re); im = fmaf(ssl3[5], pim, cc3[5] * im);
        }

        // ---- probs -> WH butterfly -> <Z_q> at remapped lanes ----
        float p = fmaf(re, re, im * im);
        { float pp = xor1f(p);               p = pp - xsign(p, nm[5]); }
        { float pp = xor2f(p);               p = pp - xsign(p, nm[4]); }
        { float pp = __shfl_xor(p, 4, 64);   p = pp - xsign(p, nm[3]); }
        { float pp = __shfl_xor(p, 8, 64);   p = pp - xsign(p, nm[2]); }
        { float pp = __shfl_xor(p, 16, 64);  p = pp - xsign(p, nm[1]); }
        { float pp = __shfl_xor(p, 32, 64);  p = pp - xsign(p, nm[0]); }

        float upd = bqr;
        upd = fmaf(rdlane(p, 44), wqr[0], upd);
        upd = fmaf(rdlane(p, 26), wqr[1], upd);
        upd = fmaf(rdlane(p, 13), wqr[2], upd);
        upd = fmaf(rdlane(p, 38), wqr[3], upd);
        upd = fmaf(rdlane(p, 51), wqr[4], upd);
        upd = fmaf(rdlane(p, 25), wqr[5], upd);
        hh = h + upd;
        xpre = xnext;
    }

    float contrib = (lane < 32) ? hh * wor : 0.0f;
    #pragma unroll
    for (int off = 32; off >= 1; off >>= 1)
        contrib += __shfl_xor(contrib, off, 64);
    if (lane == 0) out[b] = fast_sig(contrib + bo[0]);
}

extern "C" void kernel_launch(void* const* d_in, const int* in_sizes, int n_in,
                              void* d_out, int out_size, void* d_ws, size_t ws_size,
                              hipStream_t stream)
{
    const float* x    = (const float*)d_in[0];
    const float* cw1  = (const float*)d_in[1];
    const float* cb1  = (const float*)d_in[2];
    const float* cw2  = (const float*)d_in[3];
    const float* cb2  = (const float*)d_in[4];
    const float* cw3  = (const float*)d_in[5];
    const float* cb3  = (const float*)d_in[6];
    const float* W_ih = (const float*)d_in[7];
    const float* W_hh = (const float*)d_in[8];
    const float* b_ih = (const float*)d_in[9];
    const float* b_hh = (const float*)d_in[10];
    const float* qw   = (const float*)d_in[11];
    const float* Wq   = (const float*)d_in[12];
    const float* bq   = (const float*)d_in[13];
    const float* Wo   = (const float*)d_in[14];
    const float* bo   = (const float*)d_in[15];

    float* tcn = (float*)d_ws;  // [4096][256][32] f32 = 128 MiB scratch

    hipLaunchKernelGGL(tcn_kernel, dim3(B_TOT), dim3(256), 0, stream,
                       x, cw1, cb1, cw2, cb2, cw3, cb3, tcn);
    hipLaunchKernelGGL(scan_kernel, dim3(B_TOT), dim3(64), 0, stream,
                       tcn, W_ih, W_hh, b_ih, b_hh, qw, Wq, bq, Wo, bo,
                       (float*)d_out);
}